// Round 3
// baseline (275.285 us; speedup 1.0000x reference)
//
#include <hip/hip_runtime.h>
#include <hip/hip_bf16.h>
#include <hip/hip_cooperative_groups.h>

namespace cg = cooperative_groups;

#define VOCAB 100000
#define EMBED 64
#define SENT  20
#define MEM   50
#define BATCH 32
#define HOPS  3

// 4 gather sets: t=0 -> A (m for hop0); t=1..3 -> C[t-1] (c for hop t-1, m for hop t).
// Exploits m_h == c_{h-1} (same table, same words, same encoding).
#define NSET   4
#define NSLOT  (NSET * BATCH * MEM)   // 6400 sentence slots (+32 query slots)
#define GRID   512
#define NWAVES (GRID * 4)             // 2048 waves grid-stride over 6432 slots

__device__ __forceinline__ float bfr(unsigned short x) {
    union { unsigned int u; float f; } cv;
    cv.u = ((unsigned int)x) << 16;
    return cv.f;
}

// Runtime dtype probe: enc row 19 (last) is exactly 1.0 everywhere.
// bf16 storage: dword 639 packs elements 1278,1279 = (1.0bf,1.0bf) = 0x3F803F80.
__device__ __forceinline__ bool is_bf16(const void* enc) {
    return ((const unsigned int*)enc)[639] == 0x3F803F80u;
}

template<bool BF>
__device__ __forceinline__ float ldT(const void* p, size_t idx) {
    if constexpr (BF) return bfr(((const unsigned short*)p)[idx]);
    else              return ((const float*)p)[idx];
}

__device__ __forceinline__ float wave_sum(float d) {
#pragma unroll
    for (int off = 32; off > 0; off >>= 1) d += __shfl_xor(d, off, 64);
    return d;
}

// ---- Phase 1: position-encoded sentence gathers, full-width grid-stride ----
// slot < 6400: mc_ws[slot][e] = sum_s T_t[w_s][e]*enc[s][e]  (slot = t*1600 + b*50 + mm)
// slot 6400..6431: u0g[slot-6400][e]
template<bool BF>
__device__ __forceinline__ void phase1(const int* __restrict__ stories,
                                       const int* __restrict__ queries,
                                       const void* __restrict__ A,
                                       const void* __restrict__ C,
                                       const void* __restrict__ enc,
                                       float* __restrict__ mc_ws,
                                       float* __restrict__ u0g)
{
    const int tid = threadIdx.x;
    const int e   = tid & 63;
    const int gw  = blockIdx.x * 4 + (tid >> 6);
    const size_t VE = (size_t)VOCAB * EMBED;

    float encr[SENT];
#pragma unroll
    for (int s = 0; s < SENT; ++s) encr[s] = ldT<BF>(enc, s * EMBED + e);

    for (int slot = gw; slot < NSLOT + BATCH; slot += NWAVES) {
        if (slot < NSLOT) {
            const int t  = slot / (BATCH * MEM);
            const int bm = slot % (BATCH * MEM);
            const void* T   = (t == 0) ? A : C;
            const size_t to = (t == 0) ? 0 : (size_t)(t - 1) * VE;

            int wst = (e < SENT) ? stories[bm * SENT + e] : 0;
            float acc = 0.f;
#pragma unroll
            for (int s = 0; s < SENT; ++s) {
                int w = __shfl(wst, s, 64);
                acc += ldT<BF>(T, to + (size_t)w * EMBED + e) * encr[s];
            }
            mc_ws[slot * EMBED + e] = acc;
        } else {
            const int b = slot - NSLOT;
            int wq = (e < SENT) ? queries[b * SENT + e] : 0;
            float u = 0.f;
#pragma unroll
            for (int s = 0; s < SENT; ++s) {
                int w = __shfl(wq, s, 64);
                u += ldT<BF>(A, (size_t)w * EMBED + e) * encr[s];
            }
            u0g[b * EMBED + e] = u;
        }
    }
}

// ---- Phase 3 body: one vocab row dot 32 batch vectors (proven GEMV) ----
template<bool BF>
__device__ __forceinline__ void out_one(const float* __restrict__ su,
                                        const void* __restrict__ Cbase,
                                        void* __restrict__ out, int v)
{
    const size_t c2_off = (size_t)2 * VOCAB * EMBED;
    float row[EMBED];
    if constexpr (BF) {
        const uint4* rp = (const uint4*)((const unsigned short*)Cbase + c2_off + (size_t)v * EMBED);
#pragma unroll
        for (int i = 0; i < 8; ++i) {
            uint4 r = rp[i];
            row[i*8 + 0] = bfr((unsigned short)(r.x & 0xffff));
            row[i*8 + 1] = bfr((unsigned short)(r.x >> 16));
            row[i*8 + 2] = bfr((unsigned short)(r.y & 0xffff));
            row[i*8 + 3] = bfr((unsigned short)(r.y >> 16));
            row[i*8 + 4] = bfr((unsigned short)(r.z & 0xffff));
            row[i*8 + 5] = bfr((unsigned short)(r.z >> 16));
            row[i*8 + 6] = bfr((unsigned short)(r.w & 0xffff));
            row[i*8 + 7] = bfr((unsigned short)(r.w >> 16));
        }
    } else {
        const float4* rp = (const float4*)((const float*)Cbase + c2_off + (size_t)v * EMBED);
#pragma unroll
        for (int i = 0; i < 16; ++i) {
            float4 r = rp[i];
            row[i*4 + 0] = r.x; row[i*4 + 1] = r.y;
            row[i*4 + 2] = r.z; row[i*4 + 3] = r.w;
        }
    }

    float res[BATCH];
#pragma unroll
    for (int bb = 0; bb < BATCH; ++bb) {
        const float4* sp = (const float4*)(su + bb * EMBED);
        float acc = 0.f;
#pragma unroll
        for (int e4 = 0; e4 < 16; ++e4) {
            float4 us = sp[e4];
            acc += row[e4*4+0]*us.x + row[e4*4+1]*us.y
                 + row[e4*4+2]*us.z + row[e4*4+3]*us.w;
        }
        res[bb] = acc;
    }

    if constexpr (BF) {
        unsigned short* ob = (unsigned short*)out;
#pragma unroll
        for (int bb = 0; bb < BATCH; ++bb) {
            __hip_bfloat16 h = __float2bfloat16(res[bb]);
            ob[(size_t)bb * VOCAB + v] = *(unsigned short*)&h;
        }
    } else {
        float* of = (float*)out;
#pragma unroll
        for (int bb = 0; bb < BATCH; ++bb)
            of[(size_t)bb * VOCAB + v] = res[bb];
    }
}

// ---- Fused cooperative kernel: gather -> sync -> recurrence -> sync -> out ----
__global__ __launch_bounds__(256, 2) void k_all(
    const int* __restrict__ stories,   // [32,50,20]
    const int* __restrict__ queries,   // [32,20]
    const void* __restrict__ A,        // [V,64]
    const void* __restrict__ C,        // [3,V,64]
    const void* __restrict__ enc,      // [20,64]
    float* __restrict__ mc_ws,         // [6400,64]
    float* __restrict__ u0g,           // [32,64]
    float* __restrict__ u3g,           // [32,64]
    void* __restrict__ out)            // [32,V]
{
    __shared__ float smem[BATCH * EMBED];   // 8 KB; phase2 uses [0,320), phase3 all
    cg::grid_group grid = cg::this_grid();

    const bool bf = is_bf16(enc);
    const int tid = threadIdx.x;

    // ---------------- Phase 1: full-width gathers ----------------
    if (bf) phase1<true >(stories, queries, A, C, enc, mc_ws, u0g);
    else    phase1<false>(stories, queries, A, C, enc, mc_ws, u0g);

    grid.sync();

    // ---------------- Phase 2: 3-hop recurrence (blocks 0..31, one batch each) ----
    // mc_ws is L2-hot (1.6 MB just written); read directly, no LDS stage.
    if (blockIdx.x < BATCH) {
        const int b    = blockIdx.x;
        const int lane = tid & 63;
        const int widx = tid >> 6;
        float* uls = smem;          // [64]
        float* ols = smem + EMBED;  // [4][64]

        if (tid < EMBED) uls[tid] = u0g[b * EMBED + tid];
        __syncthreads();

        for (int hop = 0; hop < HOPS; ++hop) {
            // dot: lane mm computes <m[mm], u> (all 4 waves redundantly)
            float d = 0.f;
            if (lane < MEM) {
                const float* row = mc_ws +
                    ((size_t)hop * BATCH * MEM + (size_t)b * MEM + lane) * EMBED;
#pragma unroll
                for (int e2 = 0; e2 < EMBED; ++e2) d += row[e2] * uls[e2];
            }
            // softmax over lanes 0..49 (in-lane, per wave)
            float x  = (lane < MEM) ? d : -3.4e38f;
            float mx = x;
#pragma unroll
            for (int off = 32; off > 0; off >>= 1) mx = fmaxf(mx, __shfl_xor(mx, off, 64));
            float ex = (lane < MEM) ? __expf(x - mx) : 0.f;
            float sm = wave_sum(ex);
            float p  = ex / sm;

            // weighted sum: wave w covers mm = 13w .. 13w+12 (w3: 39..49)
            float o = 0.f;
            const float* crow = mc_ws +
                ((size_t)(hop + 1) * BATCH * MEM + (size_t)b * MEM) * EMBED;
#pragma unroll
            for (int k = 0; k < 13; ++k) {
                int mm = widx * 13 + k;
                if (mm < MEM)
                    o += __shfl(p, mm, 64) * crow[mm * EMBED + lane];
            }
            ols[widx * EMBED + lane] = o;
            __syncthreads();
            if (tid < EMBED)
                uls[tid] += ols[0*EMBED+tid] + ols[1*EMBED+tid]
                          + ols[2*EMBED+tid] + ols[3*EMBED+tid];
            __syncthreads();
        }
        if (tid < EMBED) u3g[b * EMBED + tid] = uls[tid];
    }

    grid.sync();

    // ---------------- Phase 3: out[b][v] = <u3[b], C2[v]> ----------------
    if ((size_t)blockIdx.x * 256 < VOCAB) {
        for (int i = tid; i < BATCH * EMBED; i += 256) smem[i] = u3g[i];
        __syncthreads();
        const int v = blockIdx.x * 256 + tid;
        if (v < VOCAB) {
            if (bf) out_one<true >(smem, C, out, v);
            else    out_one<false>(smem, C, out, v);
        }
    }
}

extern "C" void kernel_launch(void* const* d_in, const int* in_sizes, int n_in,
                              void* d_out, int out_size, void* d_ws, size_t ws_size,
                              hipStream_t stream)
{
    const int*  stories = (const int*)d_in[0];
    const int*  queries = (const int*)d_in[1];
    const void* A       = d_in[2];
    const void* C       = d_in[3];
    const void* enc     = d_in[4];

    float* mc_ws = (float*)d_ws;                   // [6400,64]
    float* u0g   = mc_ws + NSLOT * EMBED;          // [32,64]
    float* u3g   = u0g + BATCH * EMBED;            // [32,64]

    void* kargs[] = {
        (void*)&stories, (void*)&queries, (void*)&A, (void*)&C, (void*)&enc,
        (void*)&mc_ws, (void*)&u0g, (void*)&u3g, (void*)&d_out
    };
    hipLaunchCooperativeKernel((const void*)k_all, dim3(GRID), dim3(256),
                               kargs, 0, stream);
}

// Round 4
// 179.327 us; speedup vs baseline: 1.5351x; 1.5351x over previous
//
#include <hip/hip_runtime.h>
#include <hip/hip_bf16.h>

#define VOCAB 100000
#define EMBED 64
#define SENT  20
#define MEM   50
#define BATCH 32
#define HOPS  3

// 4 gather sets: t=0 -> A (m for hop0); t=1..3 -> C[t-1] (c for hop t-1, m for hop t).
// Exploits m_h == c_{h-1} (same table, same words, same encoding).
#define NSET  4
#define NSLOT (NSET * BATCH * MEM)   // 6400

__device__ __forceinline__ float bfr(unsigned short x) {
    union { unsigned int u; float f; } cv;
    cv.u = ((unsigned int)x) << 16;
    return cv.f;
}

// Runtime dtype probe: enc row 19 (last) is exactly 1.0 everywhere.
// bf16 storage: dword 639 packs elements 1278,1279 = (1.0bf,1.0bf) = 0x3F803F80.
__device__ __forceinline__ bool is_bf16(const void* enc) {
    return ((const unsigned int*)enc)[639] == 0x3F803F80u;
}

template<bool BF>
__device__ __forceinline__ float ldT(const void* p, size_t idx) {
    if constexpr (BF) return bfr(((const unsigned short*)p)[idx]);
    else              return ((const float*)p)[idx];
}

__device__ __forceinline__ float wave_sum(float d) {
#pragma unroll
    for (int off = 32; off > 0; off >>= 1) d += __shfl_xor(d, off, 64);
    return d;
}

// ---- gather body, dtype hoisted: one slot per wave (full-width, 6432 waves) ----
template<bool BF>
__device__ __forceinline__ void gather_body(const int* __restrict__ stories,
                                            const int* __restrict__ queries,
                                            const void* __restrict__ A,
                                            const void* __restrict__ C,
                                            const void* __restrict__ enc,
                                            float* __restrict__ mc_ws,
                                            float* __restrict__ u0g)
{
    const int tid = threadIdx.x;
    const int e   = tid & 63;
    const int gw  = blockIdx.x * 4 + (tid >> 6);
    const size_t VE = (size_t)VOCAB * EMBED;

    float encr[SENT];
#pragma unroll
    for (int s = 0; s < SENT; ++s) encr[s] = ldT<BF>(enc, s * EMBED + e);

    if (gw < NSLOT) {
        const int t  = gw / (BATCH * MEM);
        const int bm = gw % (BATCH * MEM);
        const void* T   = (t == 0) ? A : C;
        const size_t to = (t == 0) ? 0 : (size_t)(t - 1) * VE;

        int wst = (e < SENT) ? stories[bm * SENT + e] : 0;
        float acc = 0.f;
#pragma unroll
        for (int s = 0; s < SENT; ++s) {
            int w = __shfl(wst, s, 64);
            acc += ldT<BF>(T, to + (size_t)w * EMBED + e) * encr[s];
        }
        mc_ws[gw * EMBED + e] = acc;
    } else if (gw < NSLOT + BATCH) {
        const int b = gw - NSLOT;
        int wq = (e < SENT) ? queries[b * SENT + e] : 0;
        float u = 0.f;
#pragma unroll
        for (int s = 0; s < SENT; ++s) {
            int w = __shfl(wq, s, 64);
            u += ldT<BF>(A, (size_t)w * EMBED + e) * encr[s];
        }
        u0g[b * EMBED + e] = u;
    }
}

__global__ __launch_bounds__(256) void k_gather(
    const int* __restrict__ stories,   // [32,50,20]
    const int* __restrict__ queries,   // [32,20]
    const void* __restrict__ A,        // [V,64]
    const void* __restrict__ C,        // [3,V,64]
    const void* __restrict__ enc,      // [20,64]
    float* __restrict__ mc_ws,         // [6400,64]
    float* __restrict__ u0g)           // [32,64]
{
    // uniform scalar branch; each body is a clean 20-load MLP batch
    if (is_bf16(enc)) gather_body<true >(stories, queries, A, C, enc, mc_ws, u0g);
    else              gather_body<false>(stories, queries, A, C, enc, mc_ws, u0g);
}

// One block (256 thr = 4 waves) per batch. All 4 sets preloaded to LDS
// (52 KB, stride-65 pad: both row and column views conflict-free).
// 3-hop recurrence entirely from LDS.  [R0-proven verbatim]
__global__ __launch_bounds__(256) void k_recur2(
    const float* __restrict__ mc_ws,   // [4,1600,64] = [t][b*50+mm][e]
    const float* __restrict__ u0g,
    float* __restrict__ u3g)
{
    const int b    = blockIdx.x;
    const int tid  = threadIdx.x;
    const int lane = tid & 63;
    const int widx = tid >> 6;

    __shared__ float mc[NSET][MEM][65];   // 52 KB
    __shared__ float uls[EMBED];
    __shared__ float ols[4][EMBED];

    // cooperative float4 load: 4 sets x 50 rows x 16 float4 = 3200 loads
    for (int idx = tid; idx < NSET * MEM * 16; idx += 256) {
        int t  = idx / (MEM * 16);
        int r  = idx % (MEM * 16);
        int mm = r >> 4;
        int e4 = r & 15;
        const float4 v = *(const float4*)(mc_ws +
            (((size_t)t * BATCH * MEM) + (size_t)b * MEM + mm) * EMBED + e4 * 4);
        mc[t][mm][e4 * 4 + 0] = v.x;
        mc[t][mm][e4 * 4 + 1] = v.y;
        mc[t][mm][e4 * 4 + 2] = v.z;
        mc[t][mm][e4 * 4 + 3] = v.w;
    }
    if (tid < EMBED) uls[tid] = u0g[b * EMBED + tid];
    __syncthreads();

    for (int hop = 0; hop < HOPS; ++hop) {
        // dot: lane mm computes <m[mm], u> from LDS (all waves redundantly)
        float d = 0.f;
        if (lane < MEM) {
#pragma unroll
            for (int e = 0; e < EMBED; ++e)
                d += mc[hop][lane][e] * uls[e];
        }
        // softmax over lanes 0..49 (in-lane, per wave)
        float x = (lane < MEM) ? d : -3.4e38f;
        float mx = x;
#pragma unroll
        for (int off = 32; off > 0; off >>= 1) mx = fmaxf(mx, __shfl_xor(mx, off, 64));
        float ex = (lane < MEM) ? __expf(x - mx) : 0.f;
        float sm = wave_sum(ex);
        float p = ex / sm;

        // weighted sum: wave w covers mm = 13w .. 13w+12 (w3: 39..49)
        float o = 0.f;
#pragma unroll
        for (int k = 0; k < 13; ++k) {
            int mm = widx * 13 + k;
            if (mm < MEM)
                o += __shfl(p, mm, 64) * mc[hop + 1][mm][lane];
        }
        ols[widx][lane] = o;
        __syncthreads();
        if (tid < EMBED)
            uls[tid] += ols[0][tid] + ols[1][tid] + ols[2][tid] + ols[3][tid];
        __syncthreads();
    }

    if (tid < EMBED) u3g[b * EMBED + tid] = uls[tid];
}

// out[b*V+v] = sum_e u3[b][e] * C[2][v][e]
// v2: no LDS staging — u3 reads are wave-uniform (indices independent of tid),
// so they scalarize to s_load / broadcast from the L1-resident 8 KB buffer.
template<bool BF>
__device__ __forceinline__ void out_body(const float* __restrict__ u,
                                         const void* __restrict__ Cbase,
                                         void* __restrict__ out, int v)
{
    const size_t c2_off = (size_t)2 * VOCAB * EMBED;
    float row[EMBED];
    if constexpr (BF) {
        const uint4* rp = (const uint4*)((const unsigned short*)Cbase + c2_off + (size_t)v * EMBED);
#pragma unroll
        for (int i = 0; i < 8; ++i) {
            uint4 r = rp[i];
            row[i*8 + 0] = bfr((unsigned short)(r.x & 0xffff));
            row[i*8 + 1] = bfr((unsigned short)(r.x >> 16));
            row[i*8 + 2] = bfr((unsigned short)(r.y & 0xffff));
            row[i*8 + 3] = bfr((unsigned short)(r.y >> 16));
            row[i*8 + 4] = bfr((unsigned short)(r.z & 0xffff));
            row[i*8 + 5] = bfr((unsigned short)(r.z >> 16));
            row[i*8 + 6] = bfr((unsigned short)(r.w & 0xffff));
            row[i*8 + 7] = bfr((unsigned short)(r.w >> 16));
        }
    } else {
        const float4* rp = (const float4*)((const float*)Cbase + c2_off + (size_t)v * EMBED);
#pragma unroll
        for (int i = 0; i < 16; ++i) {
            float4 r = rp[i];
            row[i*4 + 0] = r.x; row[i*4 + 1] = r.y;
            row[i*4 + 2] = r.z; row[i*4 + 3] = r.w;
        }
    }

    float res[BATCH];
#pragma unroll
    for (int bb = 0; bb < BATCH; ++bb) {
        const float4* sp = (const float4*)(u + bb * EMBED);   // wave-uniform
        float acc = 0.f;
#pragma unroll
        for (int e4 = 0; e4 < 16; ++e4) {
            float4 us = sp[e4];
            acc += row[e4*4+0]*us.x + row[e4*4+1]*us.y
                 + row[e4*4+2]*us.z + row[e4*4+3]*us.w;
        }
        res[bb] = acc;
    }

    if constexpr (BF) {
        unsigned short* ob = (unsigned short*)out;
#pragma unroll
        for (int bb = 0; bb < BATCH; ++bb) {
            __hip_bfloat16 h = __float2bfloat16(res[bb]);
            ob[(size_t)bb * VOCAB + v] = *(unsigned short*)&h;
        }
    } else {
        float* of = (float*)out;
#pragma unroll
        for (int bb = 0; bb < BATCH; ++bb)
            of[(size_t)bb * VOCAB + v] = res[bb];
    }
}

__global__ __launch_bounds__(256) void k_out(const float* __restrict__ u,
                                             const void* __restrict__ Cbase,
                                             const void* __restrict__ enc,
                                             void* __restrict__ out)
{
    const int v = blockIdx.x * 256 + threadIdx.x;
    if (v >= VOCAB) return;
    if (is_bf16(enc)) out_body<true >(u, Cbase, out, v);
    else              out_body<false>(u, Cbase, out, v);
}

extern "C" void kernel_launch(void* const* d_in, const int* in_sizes, int n_in,
                              void* d_out, int out_size, void* d_ws, size_t ws_size,
                              hipStream_t stream)
{
    const int*  stories = (const int*)d_in[0];
    const int*  queries = (const int*)d_in[1];
    const void* A       = d_in[2];
    const void* C       = d_in[3];
    const void* enc     = d_in[4];

    float* mc_ws = (float*)d_ws;                 // [6400,64]
    float* u0g   = mc_ws + NSLOT * EMBED;        // [32,64]
    float* u3g   = u0g + BATCH * EMBED;          // [32,64]

    const int nwaves  = NSLOT + BATCH;           // 6432
    const int nblocks = (nwaves + 3) / 4;        // 1608

    k_gather<<<nblocks, 256, 0, stream>>>(stories, queries, A, C, enc, mc_ws, u0g);
    k_recur2<<<BATCH, 256, 0, stream>>>(mc_ws, u0g, u3g);
    k_out<<<(VOCAB + 255) / 256, 256, 0, stream>>>(u3g, C, enc, d_out);
}

// Round 5
// 158.597 us; speedup vs baseline: 1.7357x; 1.1307x over previous
//
#include <hip/hip_runtime.h>
#include <hip/hip_bf16.h>

#define VOCAB 100000
#define EMBED 64
#define SENT  20
#define MEM   50
#define BATCH 32
#define HOPS  3

// 4 gather sets: t=0 -> A (m for hop0); t=1..3 -> C[t-1] (c for hop t-1, m for hop t).
// Exploits m_h == c_{h-1} (same table, same words, same encoding).
#define NSET  4
#define NSLOT (NSET * BATCH * MEM)   // 6400
#define NVT   (VOCAB / 16)           // 6250 vocab tiles (exact)

typedef __attribute__((ext_vector_type(8))) short short8v;  // 8 bf16 = 4 VGPR
typedef __attribute__((ext_vector_type(4))) float f32x4;

__device__ __forceinline__ float bfr(unsigned short x) {
    union { unsigned int u; float f; } cv;
    cv.u = ((unsigned int)x) << 16;
    return cv.f;
}

// Runtime dtype probe: enc row 19 (last) is exactly 1.0 everywhere.
// bf16 storage: dword 639 packs elements 1278,1279 = (1.0bf,1.0bf) = 0x3F803F80.
__device__ __forceinline__ bool is_bf16(const void* enc) {
    return ((const unsigned int*)enc)[639] == 0x3F803F80u;
}

template<bool BF>
__device__ __forceinline__ float ldT(const void* p, size_t idx) {
    if constexpr (BF) return bfr(((const unsigned short*)p)[idx]);
    else              return ((const float*)p)[idx];
}

__device__ __forceinline__ float wave_sum(float d) {
#pragma unroll
    for (int off = 32; off > 0; off >>= 1) d += __shfl_xor(d, off, 64);
    return d;
}

// ---- gather body, dtype hoisted: one slot per wave (full-width, 6432 waves) ----
template<bool BF>
__device__ __forceinline__ void gather_body(const int* __restrict__ stories,
                                            const int* __restrict__ queries,
                                            const void* __restrict__ A,
                                            const void* __restrict__ C,
                                            const void* __restrict__ enc,
                                            float* __restrict__ mc_ws,
                                            float* __restrict__ u0g)
{
    const int tid = threadIdx.x;
    const int e   = tid & 63;
    const int gw  = blockIdx.x * 4 + (tid >> 6);
    const size_t VE = (size_t)VOCAB * EMBED;

    float encr[SENT];
#pragma unroll
    for (int s = 0; s < SENT; ++s) encr[s] = ldT<BF>(enc, s * EMBED + e);

    if (gw < NSLOT) {
        const int t  = gw / (BATCH * MEM);
        const int bm = gw % (BATCH * MEM);
        const void* T   = (t == 0) ? A : C;
        const size_t to = (t == 0) ? 0 : (size_t)(t - 1) * VE;

        int wst = (e < SENT) ? stories[bm * SENT + e] : 0;
        float acc = 0.f;
#pragma unroll
        for (int s = 0; s < SENT; ++s) {
            int w = __shfl(wst, s, 64);
            acc += ldT<BF>(T, to + (size_t)w * EMBED + e) * encr[s];
        }
        mc_ws[gw * EMBED + e] = acc;
    } else if (gw < NSLOT + BATCH) {
        const int b = gw - NSLOT;
        int wq = (e < SENT) ? queries[b * SENT + e] : 0;
        float u = 0.f;
#pragma unroll
        for (int s = 0; s < SENT; ++s) {
            int w = __shfl(wq, s, 64);
            u += ldT<BF>(A, (size_t)w * EMBED + e) * encr[s];
        }
        u0g[b * EMBED + e] = u;
    }
}

__global__ __launch_bounds__(256) void k_gather(
    const int* __restrict__ stories,   // [32,50,20]
    const int* __restrict__ queries,   // [32,20]
    const void* __restrict__ A,        // [V,64]
    const void* __restrict__ C,        // [3,V,64]
    const void* __restrict__ enc,      // [20,64]
    float* __restrict__ mc_ws,         // [6400,64]
    float* __restrict__ u0g)           // [32,64]
{
    // uniform scalar branch; each body is a clean 20-load MLP batch
    if (is_bf16(enc)) gather_body<true >(stories, queries, A, C, enc, mc_ws, u0g);
    else              gather_body<false>(stories, queries, A, C, enc, mc_ws, u0g);
}

// One block (256 thr = 4 waves) per batch. All 4 sets preloaded to LDS
// (52 KB, stride-65 pad: both row and column views conflict-free).
// 3-hop recurrence entirely from LDS.  [R0-proven; + u3bf epilogue]
__global__ __launch_bounds__(256) void k_recur2(
    const float* __restrict__ mc_ws,   // [4,1600,64] = [t][b*50+mm][e]
    const float* __restrict__ u0g,
    float* __restrict__ u3g,           // [32,64] fp32
    unsigned short* __restrict__ u3bf) // [32,64] bf16 (for MFMA k_out path)
{
    const int b    = blockIdx.x;
    const int tid  = threadIdx.x;
    const int lane = tid & 63;
    const int widx = tid >> 6;

    __shared__ float mc[NSET][MEM][65];   // 52 KB
    __shared__ float uls[EMBED];
    __shared__ float ols[4][EMBED];

    // cooperative float4 load: 4 sets x 50 rows x 16 float4 = 3200 loads
    for (int idx = tid; idx < NSET * MEM * 16; idx += 256) {
        int t  = idx / (MEM * 16);
        int r  = idx % (MEM * 16);
        int mm = r >> 4;
        int e4 = r & 15;
        const float4 v = *(const float4*)(mc_ws +
            (((size_t)t * BATCH * MEM) + (size_t)b * MEM + mm) * EMBED + e4 * 4);
        mc[t][mm][e4 * 4 + 0] = v.x;
        mc[t][mm][e4 * 4 + 1] = v.y;
        mc[t][mm][e4 * 4 + 2] = v.z;
        mc[t][mm][e4 * 4 + 3] = v.w;
    }
    if (tid < EMBED) uls[tid] = u0g[b * EMBED + tid];
    __syncthreads();

    for (int hop = 0; hop < HOPS; ++hop) {
        // dot: lane mm computes <m[mm], u> from LDS (all waves redundantly)
        float d = 0.f;
        if (lane < MEM) {
#pragma unroll
            for (int e = 0; e < EMBED; ++e)
                d += mc[hop][lane][e] * uls[e];
        }
        // softmax over lanes 0..49 (in-lane, per wave)
        float x = (lane < MEM) ? d : -3.4e38f;
        float mx = x;
#pragma unroll
        for (int off = 32; off > 0; off >>= 1) mx = fmaxf(mx, __shfl_xor(mx, off, 64));
        float ex = (lane < MEM) ? __expf(x - mx) : 0.f;
        float sm = wave_sum(ex);
        float p = ex / sm;

        // weighted sum: wave w covers mm = 13w .. 13w+12 (w3: 39..49)
        float o = 0.f;
#pragma unroll
        for (int k = 0; k < 13; ++k) {
            int mm = widx * 13 + k;
            if (mm < MEM)
                o += __shfl(p, mm, 64) * mc[hop + 1][mm][lane];
        }
        ols[widx][lane] = o;
        __syncthreads();
        if (tid < EMBED)
            uls[tid] += ols[0][tid] + ols[1][tid] + ols[2][tid] + ols[3][tid];
        __syncthreads();
    }

    if (tid < EMBED) {
        float uv = uls[tid];
        u3g[b * EMBED + tid] = uv;
        __hip_bfloat16 h = __float2bfloat16(uv);
        u3bf[b * EMBED + tid] = *(unsigned short*)&h;
    }
}

// ---- k_out fp32 fallback: R0-proven LDS-staged per-thread dot ----
__device__ __forceinline__ void out_f32(const float* __restrict__ u,
                                        const void* __restrict__ Cbase,
                                        void* __restrict__ out)
{
    if (blockIdx.x * 256 >= VOCAB) return;
    __shared__ __align__(16) float su[BATCH * EMBED];
    for (int i = threadIdx.x; i < BATCH * EMBED; i += 256) su[i] = u[i];
    __syncthreads();
    const int v = blockIdx.x * 256 + threadIdx.x;
    if (v >= VOCAB) return;

    const size_t c2_off = (size_t)2 * VOCAB * EMBED;
    float row[EMBED];
    const float4* rp = (const float4*)((const float*)Cbase + c2_off + (size_t)v * EMBED);
#pragma unroll
    for (int i = 0; i < 16; ++i) {
        float4 r = rp[i];
        row[i*4 + 0] = r.x; row[i*4 + 1] = r.y;
        row[i*4 + 2] = r.z; row[i*4 + 3] = r.w;
    }

    float* of = (float*)out;
#pragma unroll
    for (int bb = 0; bb < BATCH; ++bb) {
        const float4* sp = (const float4*)(su + bb * EMBED);
        float acc = 0.f;
#pragma unroll
        for (int e4 = 0; e4 < 16; ++e4) {
            float4 us = sp[e4];
            acc += row[e4*4+0]*us.x + row[e4*4+1]*us.y
                 + row[e4*4+2]*us.z + row[e4*4+3]*us.w;
        }
        of[(size_t)bb * VOCAB + v] = acc;
    }
}

// ---- k_out bf16: MFMA tile GEMM  out[32 x 100000] = u3bf[32x64] . C2^T ----
// One wave per 16-column vocab tile (6250 tiles). mfma_f32_16x16x32_bf16:
//   A frag: lane holds A[lane&15][ (lane>>4)*8 .. +8 )   (16B contiguous)
//   B frag: lane holds B[(lane>>4)*8..+8][lane&15] = C2[vt*16+(lane&15)][k..] (16B contiguous)
//   D frag: col=lane&15, row=(lane>>4)*4+j   [m89-verified]
__device__ __forceinline__ void out_mfma(const unsigned short* __restrict__ ubf,
                                         const void* __restrict__ Cbase,
                                         void* __restrict__ out)
{
    const int tid  = threadIdx.x;
    const int tv   = blockIdx.x * 4 + (tid >> 6);
    if (tv >= NVT) return;
    const int lane = tid & 63;
    const int l15  = lane & 15;
    const int lh   = lane >> 4;

    const unsigned short* c2 =
        (const unsigned short*)Cbase + (size_t)2 * VOCAB * EMBED;

    // A frags (u3bf is tiny & L1/L2-hot): 2 m-tiles x 2 k-halves
    const short8v a00 = *(const short8v*)(ubf + ( 0 + l15) * EMBED +  0 + lh * 8);
    const short8v a01 = *(const short8v*)(ubf + ( 0 + l15) * EMBED + 32 + lh * 8);
    const short8v a10 = *(const short8v*)(ubf + (16 + l15) * EMBED +  0 + lh * 8);
    const short8v a11 = *(const short8v*)(ubf + (16 + l15) * EMBED + 32 + lh * 8);

    // B frags: 16 C2 rows of this vocab tile, 2 k-halves
    const unsigned short* brow = c2 + ((size_t)tv * 16 + l15) * EMBED + lh * 8;
    const short8v b0 = *(const short8v*)(brow);
    const short8v b1 = *(const short8v*)(brow + 32);

    f32x4 acc0 = {0.f, 0.f, 0.f, 0.f};
    f32x4 acc1 = {0.f, 0.f, 0.f, 0.f};
    acc0 = __builtin_amdgcn_mfma_f32_16x16x32_bf16(a00, b0, acc0, 0, 0, 0);
    acc0 = __builtin_amdgcn_mfma_f32_16x16x32_bf16(a01, b1, acc0, 0, 0, 0);
    acc1 = __builtin_amdgcn_mfma_f32_16x16x32_bf16(a10, b0, acc1, 0, 0, 0);
    acc1 = __builtin_amdgcn_mfma_f32_16x16x32_bf16(a11, b1, acc1, 0, 0, 0);

    unsigned short* ob = (unsigned short*)out;
    const int v = tv * 16 + l15;
#pragma unroll
    for (int j = 0; j < 4; ++j) {
        const int br = lh * 4 + j;
        __hip_bfloat16 h0 = __float2bfloat16(acc0[j]);
        ob[(size_t)br * VOCAB + v] = *(unsigned short*)&h0;
        __hip_bfloat16 h1 = __float2bfloat16(acc1[j]);
        ob[(size_t)(16 + br) * VOCAB + v] = *(unsigned short*)&h1;
    }
}

__global__ __launch_bounds__(256) void k_out(const float* __restrict__ u,
                                             const unsigned short* __restrict__ ubf,
                                             const void* __restrict__ Cbase,
                                             const void* __restrict__ enc,
                                             void* __restrict__ out)
{
    if (is_bf16(enc)) out_mfma(ubf, Cbase, out);
    else              out_f32(u, Cbase, out);
}

extern "C" void kernel_launch(void* const* d_in, const int* in_sizes, int n_in,
                              void* d_out, int out_size, void* d_ws, size_t ws_size,
                              hipStream_t stream)
{
    const int*  stories = (const int*)d_in[0];
    const int*  queries = (const int*)d_in[1];
    const void* A       = d_in[2];
    const void* C       = d_in[3];
    const void* enc     = d_in[4];

    float* mc_ws = (float*)d_ws;                 // [6400,64] f32
    float* u0g   = mc_ws + NSLOT * EMBED;        // [32,64] f32
    float* u3g   = u0g + BATCH * EMBED;          // [32,64] f32
    unsigned short* u3bf = (unsigned short*)(u3g + BATCH * EMBED);  // [32,64] bf16

    const int nwaves  = NSLOT + BATCH;           // 6432
    const int nblocks = (nwaves + 3) / 4;        // 1608

    // bf16 path needs ceil(6250/4)=1563 blocks; fp32 path uses first 391.
    const int noutblk = (NVT + 3) / 4;           // 1563

    k_gather<<<nblocks, 256, 0, stream>>>(stories, queries, A, C, enc, mc_ws, u0g);
    k_recur2<<<BATCH, 256, 0, stream>>>(mc_ws, u0g, u3g, u3bf);
    k_out<<<noutblk, 256, 0, stream>>>(u3g, u3bf, C, enc, d_out);
}